// Round 1
// 235.996 us; speedup vs baseline: 1.0625x; 1.0625x over previous
//
#include <hip/hip_runtime.h>

#define NN 100000
#define NE 1600000
#define DD 64
#define P    1563    // 64-row partitions: p = r >> 6  (ceil(100000/64))
#define NBK  782     // binning blocks, 2048 edges each
#define PCAP 1536    // slab records per partition (mean 1024, ~16 sigma)
#define ECAP 1536    // LDS padded edge buffer (padded mean ~1248, ~8 sigma)

__device__ __forceinline__ unsigned short f2bfu(float f) {
    union { float f; unsigned u; } c; c.f = f;
    unsigned lsb = (c.u >> 16) & 1u;
    c.u += 0x7FFFu + lsb;
    return (unsigned short)(c.u >> 16);
}

typedef short v8s __attribute__((ext_vector_type(8)));
typedef float v4f __attribute__((ext_vector_type(4)));

// ===== K1: fused bin+scatter: LDS hist -> global range reserve -> slab write =====
// Replaces old count/ptot/pbase/off/scatter (5 kernels). Order within a
// partition is non-deterministic (atomic), which only permutes f32 add order.
__global__ __launch_bounds__(256) void bin_scatter_kernel(
    const int* __restrict__ row, const int* __restrict__ col,
    const float* __restrict__ val, int* __restrict__ gcur,
    int2* __restrict__ slab)
{
    __shared__ int hist[P];                  // 6252 B
    int b = blockIdx.x, t = threadIdx.x;
    for (int i = t; i < P; i += 256) hist[i] = 0;
    __syncthreads();

    int4 r[2], c[2]; float4 v[2]; bool ok[2];
#pragma unroll
    for (int h = 0; h < 2; ++h) {
        int e = b * 2048 + h * 1024 + t * 4;
        ok[h] = (e + 3 < NE);
        if (ok[h]) {
            r[h] = *(const int4*)(row + e);
            c[h] = *(const int4*)(col + e);
            v[h] = *(const float4*)(val + e);
            atomicAdd(&hist[r[h].x >> 6], 1);
            atomicAdd(&hist[r[h].y >> 6], 1);
            atomicAdd(&hist[r[h].z >> 6], 1);
            atomicAdd(&hist[r[h].w >> 6], 1);
        }
    }
    __syncthreads();
    // reserve per-partition global ranges; hist becomes intra-block cursor
    for (int i = t; i < P; i += 256) {
        int cnt = hist[i];
        hist[i] = cnt ? atomicAdd(&gcur[i], cnt) : 0;
    }
    __syncthreads();
#pragma unroll
    for (int h = 0; h < 2; ++h) {
        if (ok[h]) {
            int p0 = r[h].x >> 6, p1 = r[h].y >> 6;
            int p2 = r[h].z >> 6, p3 = r[h].w >> 6;
            int q0 = atomicAdd(&hist[p0], 1);
            int q1 = atomicAdd(&hist[p1], 1);
            int q2 = atomicAdd(&hist[p2], 1);
            int q3 = atomicAdd(&hist[p3], 1);
            if (q0 < PCAP) slab[(size_t)p0 * PCAP + q0] =
                make_int2(c[h].x | ((r[h].x & 63) << 20), __float_as_int(v[h].x));
            if (q1 < PCAP) slab[(size_t)p1 * PCAP + q1] =
                make_int2(c[h].y | ((r[h].y & 63) << 20), __float_as_int(v[h].y));
            if (q2 < PCAP) slab[(size_t)p2 * PCAP + q2] =
                make_int2(c[h].z | ((r[h].z & 63) << 20), __float_as_int(v[h].z));
            if (q3 < PCAP) slab[(size_t)p3 * PCAP + q3] =
                make_int2(c[h].w | ((r[h].w & 63) << 20), __float_as_int(v[h].w));
        }
    }
}

// ===== K2: fused in-LDS counting sort + pull-SpMM (agg -> bf16) =====
// Per block: one 64-row partition. Sort its edges into 8-padded per-row runs
// entirely in LDS, then aggregate with 4 gathers in flight per wave.
__global__ __launch_bounds__(256, 6) void sort_pull_kernel(
    const float* __restrict__ x, const int* __restrict__ gcur,
    const int2* __restrict__ slab, unsigned short* __restrict__ aggb)
{
    __shared__ int2 ebuf[ECAP];              // 12288 B
    __shared__ int rcnt[64];
    __shared__ int pscan[64];
    __shared__ int rcur[64];
    __shared__ int pstart[65];               // total ~13.3 KB -> 6 blocks/CU

    int p = blockIdx.x, t = threadIdx.x;
    int np = min(gcur[p], PCAP);
    const int2* sp = slab + (size_t)p * PCAP;

    if (t < 64) rcnt[t] = 0;
    __syncthreads();
    for (int i = t; i < np; i += 256)
        atomicAdd(&rcnt[(sp[i].x >> 20) & 63], 1);
    __syncthreads();
    if (t < 64) pscan[t] = (rcnt[t] + 7) & ~7;   // pad rows to multiple of 8
    __syncthreads();
    for (int off = 1; off < 64; off <<= 1) {
        int u = 0;
        if (t < 64 && t >= off) u = pscan[t - off];
        __syncthreads();
        if (t < 64) pscan[t] += u;
        __syncthreads();
    }
    if (t < 64) pstart[t + 1] = min(pscan[t], ECAP);
    if (t == 0) pstart[0] = 0;
    __syncthreads();
    if (t < 64) {
        rcur[t] = pstart[t];
        int s = min(pstart[t] + rcnt[t], ECAP);
        int e = pstart[t + 1];
        for (int j = s; j < e; ++j) ebuf[j] = make_int2(0, 0);  // zero pads
    }
    __syncthreads();
    for (int i = t; i < np; i += 256) {
        int2 rc = sp[i];
        int pos = atomicAdd(&rcur[(rc.x >> 20) & 63], 1);
        if (pos < ECAP) ebuf[pos] = make_int2(rc.x & 0x1FFFF, rc.y);
    }
    __syncthreads();

    // aggregation: 4 waves x 16 rows; 4 edge-slots (q) x 16 dim-lanes (sub)
    int lane = t & 63, wv = t >> 6;
    int sub = lane & 15, q = lane >> 4;
    int nb0 = p * 64;
    for (int rr = 0; rr < 16; ++rr) {
        int r = wv * 16 + rr;
        int start = pstart[r];
        int cc = (pstart[r + 1] - start) >> 3;   // padded 8-chunks
        float4 acc = make_float4(0.f, 0.f, 0.f, 0.f);
        int ch = 0;
        for (; ch + 2 <= cc; ch += 2) {
            int2 r0 = ebuf[start + ch * 8 + q];
            int2 r1 = ebuf[start + ch * 8 + 4 + q];
            int2 r2 = ebuf[start + ch * 8 + 8 + q];
            int2 r3 = ebuf[start + ch * 8 + 12 + q];
            float4 f0 = *(const float4*)(x + (size_t)r0.x * DD + sub * 4);
            float4 f1 = *(const float4*)(x + (size_t)r1.x * DD + sub * 4);
            float4 f2 = *(const float4*)(x + (size_t)r2.x * DD + sub * 4);
            float4 f3 = *(const float4*)(x + (size_t)r3.x * DD + sub * 4);
            float v0 = __int_as_float(r0.y), v1 = __int_as_float(r1.y);
            float v2 = __int_as_float(r2.y), v3 = __int_as_float(r3.y);
            acc.x = fmaf(v0, f0.x, acc.x); acc.y = fmaf(v0, f0.y, acc.y);
            acc.z = fmaf(v0, f0.z, acc.z); acc.w = fmaf(v0, f0.w, acc.w);
            acc.x = fmaf(v1, f1.x, acc.x); acc.y = fmaf(v1, f1.y, acc.y);
            acc.z = fmaf(v1, f1.z, acc.z); acc.w = fmaf(v1, f1.w, acc.w);
            acc.x = fmaf(v2, f2.x, acc.x); acc.y = fmaf(v2, f2.y, acc.y);
            acc.z = fmaf(v2, f2.z, acc.z); acc.w = fmaf(v2, f2.w, acc.w);
            acc.x = fmaf(v3, f3.x, acc.x); acc.y = fmaf(v3, f3.y, acc.y);
            acc.z = fmaf(v3, f3.z, acc.z); acc.w = fmaf(v3, f3.w, acc.w);
        }
        if (ch < cc) {
            int2 r0 = ebuf[start + ch * 8 + q];
            int2 r1 = ebuf[start + ch * 8 + 4 + q];
            float4 f0 = *(const float4*)(x + (size_t)r0.x * DD + sub * 4);
            float4 f1 = *(const float4*)(x + (size_t)r1.x * DD + sub * 4);
            float v0 = __int_as_float(r0.y), v1 = __int_as_float(r1.y);
            acc.x = fmaf(v0, f0.x, acc.x); acc.y = fmaf(v0, f0.y, acc.y);
            acc.z = fmaf(v0, f0.z, acc.z); acc.w = fmaf(v0, f0.w, acc.w);
            acc.x = fmaf(v1, f1.x, acc.x); acc.y = fmaf(v1, f1.y, acc.y);
            acc.z = fmaf(v1, f1.z, acc.z); acc.w = fmaf(v1, f1.w, acc.w);
        }
        acc.x += __shfl_xor(acc.x, 16, 64); acc.y += __shfl_xor(acc.y, 16, 64);
        acc.z += __shfl_xor(acc.z, 16, 64); acc.w += __shfl_xor(acc.w, 16, 64);
        acc.x += __shfl_xor(acc.x, 32, 64); acc.y += __shfl_xor(acc.y, 32, 64);
        acc.z += __shfl_xor(acc.z, 32, 64); acc.w += __shfl_xor(acc.w, 32, 64);

        int node = nb0 + r;
        if (q == 0 && node < NN) {
            uint2 pk;
            pk.x = (unsigned)f2bfu(acc.x) | ((unsigned)f2bfu(acc.y) << 16);
            pk.y = (unsigned)f2bfu(acc.z) | ((unsigned)f2bfu(acc.w) << 16);
            *(uint2*)(aggb + (size_t)node * DD + sub * 4) = pk;
        }
    }
}

// ===== K3: MFMA transform: h=relu(bf16 GEMM + b); rownorm; sum hops =====
// x is converted f32->bf16 inline (xb pass eliminated).
// mfma_f32_16x16x32_bf16: A[m=lane&15][k=quad*8+j]; C/D: col n=lane&15, row m=quad*4+reg.
__global__ __launch_bounds__(256) void mfma_transform_kernel(
    const float* __restrict__ x, const unsigned short* __restrict__ aggb,
    const float* __restrict__ W0, const float* __restrict__ b0,
    const float* __restrict__ s0, const float* __restrict__ o0,
    const float* __restrict__ W1, const float* __restrict__ b1,
    const float* __restrict__ s1, const float* __restrict__ o1,
    float* __restrict__ out)
{
    int t = threadIdx.x;
    int lane = t & 63, wv = t >> 6;
    int l15 = lane & 15, q = lane >> 4;
    int nb = (blockIdx.x * 4 + wv) * 16;     // 16 nodes per wave
    if (nb >= NN) return;                    // no barriers below

    float bia0[4], bia1[4], scl0[4], scl1[4], ofs0[4], ofs1[4];
#pragma unroll
    for (int dt = 0; dt < 4; ++dt) {
        int nidx = dt * 16 + l15;
        bia0[dt] = b0[nidx]; bia1[dt] = b1[nidx];
        scl0[dt] = s0[nidx]; scl1[dt] = s1[nidx];
        ofs0[dt] = o0[nidx]; ofs1[dt] = o1[nidx];
    }

    v8s wf0[4][2], wf1[4][2];
#pragma unroll
    for (int dt = 0; dt < 4; ++dt)
#pragma unroll
        for (int ks = 0; ks < 2; ++ks) {
            const float* p0 = W0 + (dt * 16 + l15) * 64 + ks * 32 + q * 8;
            const float* p1 = W1 + (dt * 16 + l15) * 64 + ks * 32 + q * 8;
            float4 a0 = *(const float4*)p0, a1 = *(const float4*)(p0 + 4);
            float4 c0_ = *(const float4*)p1, c1_ = *(const float4*)(p1 + 4);
            v8s w;
            w[0] = (short)f2bfu(a0.x); w[1] = (short)f2bfu(a0.y);
            w[2] = (short)f2bfu(a0.z); w[3] = (short)f2bfu(a0.w);
            w[4] = (short)f2bfu(a1.x); w[5] = (short)f2bfu(a1.y);
            w[6] = (short)f2bfu(a1.z); w[7] = (short)f2bfu(a1.w);
            wf0[dt][ks] = w;
            v8s u;
            u[0] = (short)f2bfu(c0_.x); u[1] = (short)f2bfu(c0_.y);
            u[2] = (short)f2bfu(c0_.z); u[3] = (short)f2bfu(c0_.w);
            u[4] = (short)f2bfu(c1_.x); u[5] = (short)f2bfu(c1_.y);
            u[6] = (short)f2bfu(c1_.z); u[7] = (short)f2bfu(c1_.w);
            wf1[dt][ks] = u;
        }

    // A fragments: X converted inline from f32, AGG loaded as bf16
    v8s ax[2], aa[2];
#pragma unroll
    for (int ks = 0; ks < 2; ++ks) {
        const float* px = x + (size_t)(nb + l15) * DD + ks * 32 + q * 8;
        float4 a0 = *(const float4*)px, a1 = *(const float4*)(px + 4);
        v8s w;
        w[0] = (short)f2bfu(a0.x); w[1] = (short)f2bfu(a0.y);
        w[2] = (short)f2bfu(a0.z); w[3] = (short)f2bfu(a0.w);
        w[4] = (short)f2bfu(a1.x); w[5] = (short)f2bfu(a1.y);
        w[6] = (short)f2bfu(a1.z); w[7] = (short)f2bfu(a1.w);
        ax[ks] = w;
        aa[ks] = *(const v8s*)(aggb + (size_t)(nb + l15) * DD + ks * 32 + q * 8);
    }

    v4f c0[4], c1[4];
#pragma unroll
    for (int dt = 0; dt < 4; ++dt) {
        c0[dt] = (v4f){bia0[dt], bia0[dt], bia0[dt], bia0[dt]};
        c1[dt] = (v4f){bia1[dt], bia1[dt], bia1[dt], bia1[dt]};
    }
#pragma unroll
    for (int dt = 0; dt < 4; ++dt) {
        c0[dt] = __builtin_amdgcn_mfma_f32_16x16x32_bf16(ax[0], wf0[dt][0], c0[dt], 0, 0, 0);
        c0[dt] = __builtin_amdgcn_mfma_f32_16x16x32_bf16(ax[1], wf0[dt][1], c0[dt], 0, 0, 0);
        c1[dt] = __builtin_amdgcn_mfma_f32_16x16x32_bf16(aa[0], wf1[dt][0], c1[dt], 0, 0, 0);
        c1[dt] = __builtin_amdgcn_mfma_f32_16x16x32_bf16(aa[1], wf1[dt][1], c1[dt], 0, 0, 0);
    }

    float h0v[4][4], h1v[4][4];
    float sr0[4] = {0,0,0,0}, sq0[4] = {0,0,0,0};
    float sr1[4] = {0,0,0,0}, sq1[4] = {0,0,0,0};
#pragma unroll
    for (int dt = 0; dt < 4; ++dt)
#pragma unroll
        for (int r = 0; r < 4; ++r) {
            float h = fmaxf(c0[dt][r], 0.f); h0v[dt][r] = h; sr0[r] += h; sq0[r] += h * h;
            float g = fmaxf(c1[dt][r], 0.f); h1v[dt][r] = g; sr1[r] += g; sq1[r] += g * g;
        }
#pragma unroll
    for (int off = 1; off < 16; off <<= 1) {
#pragma unroll
        for (int r = 0; r < 4; ++r) {
            sr0[r] += __shfl_xor(sr0[r], off, 64);
            sq0[r] += __shfl_xor(sq0[r], off, 64);
            sr1[r] += __shfl_xor(sr1[r], off, 64);
            sq1[r] += __shfl_xor(sq1[r], off, 64);
        }
    }

    const float inv = 1.0f / 64.0f;
#pragma unroll
    for (int r = 0; r < 4; ++r) {
        float m0 = sr0[r] * inv;
        float v0 = fmaxf(sq0[r] * inv - m0 * m0, 0.f) + 1e-9f;
        float m1 = sr1[r] * inv;
        float v1 = fmaxf(sq1[r] * inv - m1 * m1, 0.f) + 1e-9f;
        float rs0 = rsqrtf(v0), rs1 = rsqrtf(v1);
        int node = nb + q * 4 + r;
#pragma unroll
        for (int dt = 0; dt < 4; ++dt) {
            float rv = (h0v[dt][r] - m0) * scl0[dt] * rs0 + ofs0[dt]
                     + (h1v[dt][r] - m1) * scl1[dt] * rs1 + ofs1[dt];
            out[(size_t)node * DD + dt * 16 + l15] = rv;  // 64B-coalesced per quad
        }
    }
}

extern "C" void kernel_launch(void* const* d_in, const int* in_sizes, int n_in,
                              void* d_out, int out_size, void* d_ws, size_t ws_size,
                              hipStream_t stream) {
    const float* x  = (const float*)d_in[0];
    const float* ev = (const float*)d_in[1];
    const float* W0 = (const float*)d_in[2];
    const float* b0 = (const float*)d_in[3];
    const float* s0 = (const float*)d_in[4];
    const float* o0 = (const float*)d_in[5];
    const float* W1 = (const float*)d_in[6];
    const float* b1 = (const float*)d_in[7];
    const float* s1 = (const float*)d_in[8];
    const float* o1 = (const float*)d_in[9];
    const int* row = (const int*)d_in[10];
    const int* col = (const int*)d_in[11];

    // ws byte layout (64B-aligned):
    //   gcur:  0          (6252 B, pad 6400)
    //   slab:  6400       (1563*1536*8 = 19,206,144 B)
    //   aggb:  19,212,544 (12,800,000 B)   -- total ~32.0 MB
    char* wsb = (char*)d_ws;
    int*  gcur = (int*)wsb;
    int2* slab = (int2*)(wsb + 6400);
    unsigned short* aggb = (unsigned short*)(wsb + 19212544);

    hipMemsetAsync(gcur, 0, P * sizeof(int), stream);
    bin_scatter_kernel<<<NBK, 256, 0, stream>>>(row, col, ev, gcur, slab);
    sort_pull_kernel<<<P, 256, 0, stream>>>(x, gcur, slab, aggb);
    mfma_transform_kernel<<<(NN / 16 + 3) / 4, 256, 0, stream>>>(
        x, aggb, W0, b0, s0, o0, W1, b1, s1, o1, (float*)d_out);
}

// Round 2
// 216.813 us; speedup vs baseline: 1.1565x; 1.0885x over previous
//
#include <hip/hip_runtime.h>

#define NN 100000
#define NE 1600000
#define DD 64
#define P    1563    // 64-row partitions: p = r >> 6  (ceil(100000/64))
#define NBK  782     // binning blocks, 2048 edges each
#define PCAP 1536    // slab records per partition (mean 1024, ~16 sigma)
#define ECAP 1536    // LDS padded edge buffer (padded mean ~1248, ~8 sigma)
#define AGS  68      // agg LDS tile row stride in f32 words (64+4 bank pad)

__device__ __forceinline__ unsigned short f2bfu(float f) {
    union { float f; unsigned u; } c; c.f = f;
    unsigned lsb = (c.u >> 16) & 1u;
    c.u += 0x7FFFu + lsb;
    return (unsigned short)(c.u >> 16);
}

typedef short v8s __attribute__((ext_vector_type(8)));
typedef float v4f __attribute__((ext_vector_type(4)));

// ===== K0: init: zero gcur, pre-convert W0/W1 -> bf16 (replaces memset) =====
__global__ __launch_bounds__(256) void init_kernel(
    const float* __restrict__ W0, const float* __restrict__ W1,
    int* __restrict__ gcur,
    unsigned short* __restrict__ wb0, unsigned short* __restrict__ wb1)
{
    int i = blockIdx.x * 256 + threadIdx.x;     // grid 16*256 = 4096 threads
    if (i < P) gcur[i] = 0;
    if (i < DD * DD) { wb0[i] = f2bfu(W0[i]); wb1[i] = f2bfu(W1[i]); }
}

// ===== K1: fused bin+scatter: LDS hist -> global range reserve -> slab write =====
__global__ __launch_bounds__(256) void bin_scatter_kernel(
    const int* __restrict__ row, const int* __restrict__ col,
    const float* __restrict__ val, int* __restrict__ gcur,
    int2* __restrict__ slab)
{
    __shared__ int hist[P];                  // 6252 B
    int b = blockIdx.x, t = threadIdx.x;
    for (int i = t; i < P; i += 256) hist[i] = 0;
    __syncthreads();

    int4 r[2], c[2]; float4 v[2]; bool ok[2];
#pragma unroll
    for (int h = 0; h < 2; ++h) {
        int e = b * 2048 + h * 1024 + t * 4;
        ok[h] = (e + 3 < NE);
        if (ok[h]) {
            r[h] = *(const int4*)(row + e);
            c[h] = *(const int4*)(col + e);
            v[h] = *(const float4*)(val + e);
            atomicAdd(&hist[r[h].x >> 6], 1);
            atomicAdd(&hist[r[h].y >> 6], 1);
            atomicAdd(&hist[r[h].z >> 6], 1);
            atomicAdd(&hist[r[h].w >> 6], 1);
        }
    }
    __syncthreads();
    for (int i = t; i < P; i += 256) {
        int cnt = hist[i];
        hist[i] = cnt ? atomicAdd(&gcur[i], cnt) : 0;
    }
    __syncthreads();
#pragma unroll
    for (int h = 0; h < 2; ++h) {
        if (ok[h]) {
            int p0 = r[h].x >> 6, p1 = r[h].y >> 6;
            int p2 = r[h].z >> 6, p3 = r[h].w >> 6;
            int q0 = atomicAdd(&hist[p0], 1);
            int q1 = atomicAdd(&hist[p1], 1);
            int q2 = atomicAdd(&hist[p2], 1);
            int q3 = atomicAdd(&hist[p3], 1);
            if (q0 < PCAP) slab[(size_t)p0 * PCAP + q0] =
                make_int2(c[h].x | ((r[h].x & 63) << 20), __float_as_int(v[h].x));
            if (q1 < PCAP) slab[(size_t)p1 * PCAP + q1] =
                make_int2(c[h].y | ((r[h].y & 63) << 20), __float_as_int(v[h].y));
            if (q2 < PCAP) slab[(size_t)p2 * PCAP + q2] =
                make_int2(c[h].z | ((r[h].z & 63) << 20), __float_as_int(v[h].z));
            if (q3 < PCAP) slab[(size_t)p3 * PCAP + q3] =
                make_int2(c[h].w | ((r[h].w & 63) << 20), __float_as_int(v[h].w));
        }
    }
}

// ===== K2: fused in-LDS sort + pull-SpMM + MFMA transform + rownorm =====
// One block per 64-row partition. Slab is read ONCE (into registers), sorted
// into 8-padded per-row LDS runs, aggregated (f32) into a per-wave LDS tile,
// then the two-hop bf16 GEMM + rownorm runs straight out of registers/LDS.
// aggb and the separate transform kernel are gone.
__global__ __launch_bounds__(256, 4) void sort_pull_mfma_kernel(
    const float* __restrict__ x, const int* __restrict__ gcur,
    const int2* __restrict__ slab,
    const unsigned short* __restrict__ wb0, const unsigned short* __restrict__ wb1,
    const float* __restrict__ b0, const float* __restrict__ s0, const float* __restrict__ o0,
    const float* __restrict__ b1, const float* __restrict__ s1, const float* __restrict__ o1,
    float* __restrict__ out)
{
    __shared__ int2 ebuf[ECAP];              // 12288 B
    __shared__ float aggt[4][16][AGS];       // 17408 B (per-wave 16x64 f32, padded)
    __shared__ int rcnt[64];
    __shared__ int pscan[64];
    __shared__ int rcur[64];
    __shared__ int pstart[65];               // total ~30.7 KB -> 5 blocks/CU

    int p = blockIdx.x, t = threadIdx.x;
    int np = min(gcur[p], PCAP);
    const int2* sp = slab + (size_t)p * PCAP;

    // ---- phase 1: slab -> registers (single global read), count rows ----
    int2 rec[6]; int nrec = 0;
    if (t < 64) rcnt[t] = 0;
    __syncthreads();
#pragma unroll
    for (int k = 0; k < 6; ++k) {
        int i = t + k * 256;
        if (i < np) {
            rec[k] = sp[i]; ++nrec;
            atomicAdd(&rcnt[(rec[k].x >> 20) & 63], 1);
        }
    }
    __syncthreads();
    // ---- phase 2: 8-padded exclusive scan of row counts ----
    if (t < 64) pscan[t] = (rcnt[t] + 7) & ~7;
    __syncthreads();
    for (int off = 1; off < 64; off <<= 1) {
        int u = 0;
        if (t < 64 && t >= off) u = pscan[t - off];
        __syncthreads();
        if (t < 64) pscan[t] += u;
        __syncthreads();
    }
    if (t < 64) pstart[t + 1] = min(pscan[t], ECAP);
    if (t == 0) pstart[0] = 0;
    __syncthreads();
    if (t < 64) {
        rcur[t] = pstart[t];
        int s = min(pstart[t] + rcnt[t], ECAP);
        int e = pstart[t + 1];
        for (int j = s; j < e; ++j) ebuf[j] = make_int2(0, 0);  // zero pads
    }
    __syncthreads();
#pragma unroll
    for (int k = 0; k < 6; ++k) {
        if (k < nrec) {
            int pos = atomicAdd(&rcur[(rec[k].x >> 20) & 63], 1);
            if (pos < ECAP) ebuf[pos] = make_int2(rec[k].x & 0x1FFFF, rec[k].y);
        }
    }
    __syncthreads();

    // ---- phase 3: gather-aggregate; agg (f32) -> per-wave LDS tile ----
    int lane = t & 63, wv = t >> 6;
    int sub = lane & 15, q = lane >> 4;
    for (int rr = 0; rr < 16; ++rr) {
        int r = wv * 16 + rr;
        int start = pstart[r];
        int cc = (pstart[r + 1] - start) >> 3;
        float4 acc = make_float4(0.f, 0.f, 0.f, 0.f);
        int ch = 0;
        for (; ch + 2 <= cc; ch += 2) {
            int2 r0 = ebuf[start + ch * 8 + q];
            int2 r1 = ebuf[start + ch * 8 + 4 + q];
            int2 r2 = ebuf[start + ch * 8 + 8 + q];
            int2 r3 = ebuf[start + ch * 8 + 12 + q];
            float4 f0 = *(const float4*)(x + (size_t)r0.x * DD + sub * 4);
            float4 f1 = *(const float4*)(x + (size_t)r1.x * DD + sub * 4);
            float4 f2 = *(const float4*)(x + (size_t)r2.x * DD + sub * 4);
            float4 f3 = *(const float4*)(x + (size_t)r3.x * DD + sub * 4);
            float v0 = __int_as_float(r0.y), v1 = __int_as_float(r1.y);
            float v2 = __int_as_float(r2.y), v3 = __int_as_float(r3.y);
            acc.x = fmaf(v0, f0.x, acc.x); acc.y = fmaf(v0, f0.y, acc.y);
            acc.z = fmaf(v0, f0.z, acc.z); acc.w = fmaf(v0, f0.w, acc.w);
            acc.x = fmaf(v1, f1.x, acc.x); acc.y = fmaf(v1, f1.y, acc.y);
            acc.z = fmaf(v1, f1.z, acc.z); acc.w = fmaf(v1, f1.w, acc.w);
            acc.x = fmaf(v2, f2.x, acc.x); acc.y = fmaf(v2, f2.y, acc.y);
            acc.z = fmaf(v2, f2.z, acc.z); acc.w = fmaf(v2, f2.w, acc.w);
            acc.x = fmaf(v3, f3.x, acc.x); acc.y = fmaf(v3, f3.y, acc.y);
            acc.z = fmaf(v3, f3.z, acc.z); acc.w = fmaf(v3, f3.w, acc.w);
        }
        if (ch < cc) {
            int2 r0 = ebuf[start + ch * 8 + q];
            int2 r1 = ebuf[start + ch * 8 + 4 + q];
            float4 f0 = *(const float4*)(x + (size_t)r0.x * DD + sub * 4);
            float4 f1 = *(const float4*)(x + (size_t)r1.x * DD + sub * 4);
            float v0 = __int_as_float(r0.y), v1 = __int_as_float(r1.y);
            acc.x = fmaf(v0, f0.x, acc.x); acc.y = fmaf(v0, f0.y, acc.y);
            acc.z = fmaf(v0, f0.z, acc.z); acc.w = fmaf(v0, f0.w, acc.w);
            acc.x = fmaf(v1, f1.x, acc.x); acc.y = fmaf(v1, f1.y, acc.y);
            acc.z = fmaf(v1, f1.z, acc.z); acc.w = fmaf(v1, f1.w, acc.w);
        }
        acc.x += __shfl_xor(acc.x, 16, 64); acc.y += __shfl_xor(acc.y, 16, 64);
        acc.z += __shfl_xor(acc.z, 16, 64); acc.w += __shfl_xor(acc.w, 16, 64);
        acc.x += __shfl_xor(acc.x, 32, 64); acc.y += __shfl_xor(acc.y, 32, 64);
        acc.z += __shfl_xor(acc.z, 32, 64); acc.w += __shfl_xor(acc.w, 32, 64);
        if (q == 0)
            *(float4*)&aggt[wv][rr][sub * 4] = acc;   // 2-way banks (free)
    }
    // per-wave tile written by this wave only -> no barrier needed (lgkmcnt orders)

    // ---- phase 4: two-hop MFMA transform + rownorm for this wave's 16 nodes ----
    int nb0 = p * 64 + wv * 16;
    if (nb0 >= NN) return;                   // tail partitions: whole waves only

    // A fragments: hop0 = x (f32->bf16 inline), hop1 = agg from LDS tile
    v8s ax[2], aa[2];
#pragma unroll
    for (int ks = 0; ks < 2; ++ks) {
        const float* px = x + (size_t)(nb0 + sub) * DD + ks * 32 + q * 8;
        float4 a0 = *(const float4*)px, a1 = *(const float4*)(px + 4);
        v8s w;
        w[0] = (short)f2bfu(a0.x); w[1] = (short)f2bfu(a0.y);
        w[2] = (short)f2bfu(a0.z); w[3] = (short)f2bfu(a0.w);
        w[4] = (short)f2bfu(a1.x); w[5] = (short)f2bfu(a1.y);
        w[6] = (short)f2bfu(a1.z); w[7] = (short)f2bfu(a1.w);
        ax[ks] = w;
        const float* pa = &aggt[wv][sub][ks * 32 + q * 8];
        float4 g0 = *(const float4*)pa, g1 = *(const float4*)(pa + 4);
        v8s u;
        u[0] = (short)f2bfu(g0.x); u[1] = (short)f2bfu(g0.y);
        u[2] = (short)f2bfu(g0.z); u[3] = (short)f2bfu(g0.w);
        u[4] = (short)f2bfu(g1.x); u[5] = (short)f2bfu(g1.y);
        u[6] = (short)f2bfu(g1.z); u[7] = (short)f2bfu(g1.w);
        aa[ks] = u;
    }

    // dt-sequential GEMM: transient W frags keep VGPR pressure under 128
    float h0v[4][4], h1v[4][4];
    float sr0[4] = {0,0,0,0}, sq0[4] = {0,0,0,0};
    float sr1[4] = {0,0,0,0}, sq1[4] = {0,0,0,0};
#pragma unroll
    for (int dt = 0; dt < 4; ++dt) {
        int nidx = dt * 16 + sub;
        float bi0 = b0[nidx], bi1 = b1[nidx];
        v8s w00 = *(const v8s*)(wb0 + nidx * 64 + q * 8);
        v8s w01 = *(const v8s*)(wb0 + nidx * 64 + 32 + q * 8);
        v8s w10 = *(const v8s*)(wb1 + nidx * 64 + q * 8);
        v8s w11 = *(const v8s*)(wb1 + nidx * 64 + 32 + q * 8);
        v4f c0 = (v4f){bi0, bi0, bi0, bi0};
        v4f c1 = (v4f){bi1, bi1, bi1, bi1};
        c0 = __builtin_amdgcn_mfma_f32_16x16x32_bf16(ax[0], w00, c0, 0, 0, 0);
        c0 = __builtin_amdgcn_mfma_f32_16x16x32_bf16(ax[1], w01, c0, 0, 0, 0);
        c1 = __builtin_amdgcn_mfma_f32_16x16x32_bf16(aa[0], w10, c1, 0, 0, 0);
        c1 = __builtin_amdgcn_mfma_f32_16x16x32_bf16(aa[1], w11, c1, 0, 0, 0);
#pragma unroll
        for (int r = 0; r < 4; ++r) {
            float h = fmaxf(c0[r], 0.f); h0v[dt][r] = h; sr0[r] += h; sq0[r] += h * h;
            float g = fmaxf(c1[r], 0.f); h1v[dt][r] = g; sr1[r] += g; sq1[r] += g * g;
        }
    }
#pragma unroll
    for (int off = 1; off < 16; off <<= 1) {
#pragma unroll
        for (int r = 0; r < 4; ++r) {
            sr0[r] += __shfl_xor(sr0[r], off, 64);
            sq0[r] += __shfl_xor(sq0[r], off, 64);
            sr1[r] += __shfl_xor(sr1[r], off, 64);
            sq1[r] += __shfl_xor(sq1[r], off, 64);
        }
    }

    float scl0[4], scl1[4], ofs0[4], ofs1[4];
#pragma unroll
    for (int dt = 0; dt < 4; ++dt) {
        int nidx = dt * 16 + sub;
        scl0[dt] = s0[nidx]; scl1[dt] = s1[nidx];
        ofs0[dt] = o0[nidx]; ofs1[dt] = o1[nidx];
    }

    const float inv = 1.0f / 64.0f;
#pragma unroll
    for (int r = 0; r < 4; ++r) {
        float m0 = sr0[r] * inv;
        float v0 = fmaxf(sq0[r] * inv - m0 * m0, 0.f) + 1e-9f;
        float m1 = sr1[r] * inv;
        float v1 = fmaxf(sq1[r] * inv - m1 * m1, 0.f) + 1e-9f;
        float rs0 = rsqrtf(v0), rs1 = rsqrtf(v1);
        int node = nb0 + q * 4 + r;           // always < NN (whole-wave tails)
#pragma unroll
        for (int dt = 0; dt < 4; ++dt) {
            float rv = (h0v[dt][r] - m0) * scl0[dt] * rs0 + ofs0[dt]
                     + (h1v[dt][r] - m1) * scl1[dt] * rs1 + ofs1[dt];
            out[(size_t)node * DD + dt * 16 + sub] = rv;  // 64B-coalesced per quad
        }
    }
}

extern "C" void kernel_launch(void* const* d_in, const int* in_sizes, int n_in,
                              void* d_out, int out_size, void* d_ws, size_t ws_size,
                              hipStream_t stream) {
    const float* x  = (const float*)d_in[0];
    const float* ev = (const float*)d_in[1];
    const float* W0 = (const float*)d_in[2];
    const float* b0 = (const float*)d_in[3];
    const float* s0 = (const float*)d_in[4];
    const float* o0 = (const float*)d_in[5];
    const float* W1 = (const float*)d_in[6];
    const float* b1 = (const float*)d_in[7];
    const float* s1 = (const float*)d_in[8];
    const float* o1 = (const float*)d_in[9];
    const int* row = (const int*)d_in[10];
    const int* col = (const int*)d_in[11];

    // ws byte layout (64B-aligned):
    //   gcur: 0      (6252 B, pad 6400)
    //   wb0:  6400   (8192 B)
    //   wb1:  14592  (8192 B)
    //   slab: 22784  (1563*1536*8 = 19,206,144 B)  -- total ~19.2 MB
    char* wsb = (char*)d_ws;
    int*  gcur = (int*)wsb;
    unsigned short* wb0 = (unsigned short*)(wsb + 6400);
    unsigned short* wb1 = (unsigned short*)(wsb + 14592);
    int2* slab = (int2*)(wsb + 22784);

    init_kernel<<<16, 256, 0, stream>>>(W0, W1, gcur, wb0, wb1);
    bin_scatter_kernel<<<NBK, 256, 0, stream>>>(row, col, ev, gcur, slab);
    sort_pull_mfma_kernel<<<P, 256, 0, stream>>>(
        x, gcur, slab, wb0, wb1, b0, s0, o0, b1, s1, o1, (float*)d_out);
}

// Round 3
// 202.212 us; speedup vs baseline: 1.2400x; 1.0722x over previous
//
#include <hip/hip_runtime.h>

#define NN 100000
#define NE 1600000
#define DD 64
#define P    1563    // 64-row fine partitions: f = row >> 6
#define NB   196     // 512-row coarse buckets: b = row >> 9 (99999>>9 = 195)
#define NBK1 391     // K1 blocks, 4096 edges each (391*4096 >= NE)
#define BCAP 10240   // records per bucket slab (mean 8192, ~23 sigma)
#define PCAP 1536    // records per fine partition slab (mean 1024, ~16 sigma)
#define ECAP 1536    // LDS padded edge buffer in K3

__device__ __forceinline__ unsigned short f2bfu(float f) {
    union { float f; unsigned u; } c; c.f = f;
    unsigned lsb = (c.u >> 16) & 1u;
    c.u += 0x7FFFu + lsb;
    return (unsigned short)(c.u >> 16);
}

typedef short v8s __attribute__((ext_vector_type(8)));
typedef float v4f __attribute__((ext_vector_type(4)));

// ===== K0: init: zero bucket cursors, pre-convert W0/W1 -> bf16 =====
__global__ __launch_bounds__(256) void init_kernel(
    const float* __restrict__ W0, const float* __restrict__ W1,
    int* __restrict__ gbcur,
    unsigned short* __restrict__ wb0, unsigned short* __restrict__ wb1)
{
    int i = blockIdx.x * 256 + threadIdx.x;     // grid 16*256 = 4096 threads
    if (i < NB) gbcur[i] = 0;
    if (i < DD * DD) { wb0[i] = f2bfu(W0[i]); wb1[i] = f2bfu(W1[i]); }
}

// ===== K1: coarse bucket scatter (196 buckets -> ~21-record coalesced runs) =====
// Record: (col | row_local9 << 20, val); row_local9 = row & 511.
__global__ __launch_bounds__(256) void bucket_scatter_kernel(
    const int* __restrict__ row, const int* __restrict__ col,
    const float* __restrict__ val, int* __restrict__ gbcur,
    int2* __restrict__ bslab)
{
    __shared__ int hist[NB];                 // 784 B
    int b = blockIdx.x, t = threadIdx.x;
    if (t < NB) hist[t] = 0;
    __syncthreads();

    int4 r[4], c[4]; float4 v[4]; bool ok[4];
#pragma unroll
    for (int h = 0; h < 4; ++h) {
        int e = b * 4096 + h * 1024 + t * 4;
        ok[h] = (e + 3 < NE);
        if (ok[h]) {
            r[h] = *(const int4*)(row + e);
            c[h] = *(const int4*)(col + e);
            v[h] = *(const float4*)(val + e);
            atomicAdd(&hist[r[h].x >> 9], 1);
            atomicAdd(&hist[r[h].y >> 9], 1);
            atomicAdd(&hist[r[h].z >> 9], 1);
            atomicAdd(&hist[r[h].w >> 9], 1);
        }
    }
    __syncthreads();
    if (t < NB) {
        int cnt = hist[t];
        hist[t] = cnt ? atomicAdd(&gbcur[t], cnt) : 0;
    }
    __syncthreads();
#pragma unroll
    for (int h = 0; h < 4; ++h) {
        if (ok[h]) {
            int b0_ = r[h].x >> 9, b1_ = r[h].y >> 9;
            int b2_ = r[h].z >> 9, b3_ = r[h].w >> 9;
            int q0 = atomicAdd(&hist[b0_], 1);
            int q1 = atomicAdd(&hist[b1_], 1);
            int q2 = atomicAdd(&hist[b2_], 1);
            int q3 = atomicAdd(&hist[b3_], 1);
            if (q0 < BCAP) bslab[(size_t)b0_ * BCAP + q0] =
                make_int2(c[h].x | ((r[h].x & 511) << 20), __float_as_int(v[h].x));
            if (q1 < BCAP) bslab[(size_t)b1_ * BCAP + q1] =
                make_int2(c[h].y | ((r[h].y & 511) << 20), __float_as_int(v[h].y));
            if (q2 < BCAP) bslab[(size_t)b2_ * BCAP + q2] =
                make_int2(c[h].z | ((r[h].z & 511) << 20), __float_as_int(v[h].z));
            if (q3 < BCAP) bslab[(size_t)b3_ * BCAP + q3] =
                make_int2(c[h].w | ((r[h].w & 511) << 20), __float_as_int(v[h].w));
        }
    }
}

// ===== K2: fine scatter: one block per bucket -> its 8 fine partitions =====
// Exclusive ownership (fine partition f only receives from bucket f>>3):
// LDS cursors only, no global atomics; writes = 8 sequential L2-local streams.
__global__ __launch_bounds__(256) void fine_scatter_kernel(
    const int* __restrict__ gbcur, const int2* __restrict__ bslab,
    int2* __restrict__ fslab, int* __restrict__ fcnt)
{
    __shared__ int cur[8];
    int b = blockIdx.x, t = threadIdx.x;
    int nb = min(gbcur[b], BCAP);
    const int2* bp = bslab + (size_t)b * BCAP;
    if (t < 8) cur[t] = 0;
    __syncthreads();
    for (int i = t; i < nb; i += 256) {
        int2 rc = bp[i];
        int rl = (rc.x >> 20) & 511;
        int lp = rl >> 6;
        int pos = atomicAdd(&cur[lp], 1);
        if (pos < PCAP)
            fslab[(size_t)(b * 8 + lp) * PCAP + pos] =
                make_int2((rc.x & 0x1FFFF) | ((rl & 63) << 20), rc.y);
    }
    __syncthreads();
    if (t < 8) fcnt[b * 8 + t] = min(cur[t], PCAP);
}

// ===== K3: fused in-LDS sort + pull-SpMM + MFMA transform + rownorm =====
// Agg tile stored as packed bf16 (same rounding as the old aggb path) ->
// LDS 22.5 KB -> 7 blocks/CU for better gather-latency hiding.
__global__ __launch_bounds__(256, 7) void sort_pull_mfma_kernel(
    const float* __restrict__ x, const int* __restrict__ fcnt,
    const int2* __restrict__ fslab,
    const unsigned short* __restrict__ wb0, const unsigned short* __restrict__ wb1,
    const float* __restrict__ b0, const float* __restrict__ s0, const float* __restrict__ o0,
    const float* __restrict__ b1, const float* __restrict__ s1, const float* __restrict__ o1,
    float* __restrict__ out)
{
    __shared__ int2 ebuf[ECAP];              // 12288 B
    __shared__ unsigned aggt[4][16][36];     // 9216 B (16x64 bf16/wave, 16B-aligned rows)
    __shared__ int rcnt[64];
    __shared__ int pscan[64];
    __shared__ int rcur[64];
    __shared__ int pstart[65];               // total ~22.5 KB -> 7 blocks/CU

    int p = blockIdx.x, t = threadIdx.x;
    int np = fcnt[p];
    const int2* sp = fslab + (size_t)p * PCAP;

    // ---- phase 1: slab -> registers (single global read), count rows ----
    int2 rec[6]; int nrec = 0;
    if (t < 64) rcnt[t] = 0;
    __syncthreads();
#pragma unroll
    for (int k = 0; k < 6; ++k) {
        int i = t + k * 256;
        if (i < np) {
            rec[k] = sp[i]; ++nrec;
            atomicAdd(&rcnt[(rec[k].x >> 20) & 63], 1);
        }
    }
    __syncthreads();
    // ---- phase 2: 8-padded exclusive scan of row counts ----
    if (t < 64) pscan[t] = (rcnt[t] + 7) & ~7;
    __syncthreads();
    for (int off = 1; off < 64; off <<= 1) {
        int u = 0;
        if (t < 64 && t >= off) u = pscan[t - off];
        __syncthreads();
        if (t < 64) pscan[t] += u;
        __syncthreads();
    }
    if (t < 64) pstart[t + 1] = min(pscan[t], ECAP);
    if (t == 0) pstart[0] = 0;
    __syncthreads();
    if (t < 64) {
        rcur[t] = pstart[t];
        int s = min(pstart[t] + rcnt[t], ECAP);
        int e = pstart[t + 1];
        for (int j = s; j < e; ++j) ebuf[j] = make_int2(0, 0);  // zero pads
    }
    __syncthreads();
#pragma unroll
    for (int k = 0; k < 6; ++k) {
        if (k < nrec) {
            int pos = atomicAdd(&rcur[(rec[k].x >> 20) & 63], 1);
            if (pos < ECAP) ebuf[pos] = make_int2(rec[k].x & 0x1FFFF, rec[k].y);
        }
    }
    __syncthreads();

    // ---- phase 3: gather-aggregate; agg -> per-wave LDS tile (packed bf16) ----
    int lane = t & 63, wv = t >> 6;
    int sub = lane & 15, q = lane >> 4;
    for (int rr = 0; rr < 16; ++rr) {
        int r = wv * 16 + rr;
        int start = pstart[r];
        int cc = (pstart[r + 1] - start) >> 3;
        float4 acc = make_float4(0.f, 0.f, 0.f, 0.f);
        int ch = 0;
        for (; ch + 2 <= cc; ch += 2) {
            int2 r0 = ebuf[start + ch * 8 + q];
            int2 r1 = ebuf[start + ch * 8 + 4 + q];
            int2 r2 = ebuf[start + ch * 8 + 8 + q];
            int2 r3 = ebuf[start + ch * 8 + 12 + q];
            float4 f0 = *(const float4*)(x + (size_t)r0.x * DD + sub * 4);
            float4 f1 = *(const float4*)(x + (size_t)r1.x * DD + sub * 4);
            float4 f2 = *(const float4*)(x + (size_t)r2.x * DD + sub * 4);
            float4 f3 = *(const float4*)(x + (size_t)r3.x * DD + sub * 4);
            float v0 = __int_as_float(r0.y), v1 = __int_as_float(r1.y);
            float v2 = __int_as_float(r2.y), v3 = __int_as_float(r3.y);
            acc.x = fmaf(v0, f0.x, acc.x); acc.y = fmaf(v0, f0.y, acc.y);
            acc.z = fmaf(v0, f0.z, acc.z); acc.w = fmaf(v0, f0.w, acc.w);
            acc.x = fmaf(v1, f1.x, acc.x); acc.y = fmaf(v1, f1.y, acc.y);
            acc.z = fmaf(v1, f1.z, acc.z); acc.w = fmaf(v1, f1.w, acc.w);
            acc.x = fmaf(v2, f2.x, acc.x); acc.y = fmaf(v2, f2.y, acc.y);
            acc.z = fmaf(v2, f2.z, acc.z); acc.w = fmaf(v2, f2.w, acc.w);
            acc.x = fmaf(v3, f3.x, acc.x); acc.y = fmaf(v3, f3.y, acc.y);
            acc.z = fmaf(v3, f3.z, acc.z); acc.w = fmaf(v3, f3.w, acc.w);
        }
        if (ch < cc) {
            int2 r0 = ebuf[start + ch * 8 + q];
            int2 r1 = ebuf[start + ch * 8 + 4 + q];
            float4 f0 = *(const float4*)(x + (size_t)r0.x * DD + sub * 4);
            float4 f1 = *(const float4*)(x + (size_t)r1.x * DD + sub * 4);
            float v0 = __int_as_float(r0.y), v1 = __int_as_float(r1.y);
            acc.x = fmaf(v0, f0.x, acc.x); acc.y = fmaf(v0, f0.y, acc.y);
            acc.z = fmaf(v0, f0.z, acc.z); acc.w = fmaf(v0, f0.w, acc.w);
            acc.x = fmaf(v1, f1.x, acc.x); acc.y = fmaf(v1, f1.y, acc.y);
            acc.z = fmaf(v1, f1.z, acc.z); acc.w = fmaf(v1, f1.w, acc.w);
        }
        acc.x += __shfl_xor(acc.x, 16, 64); acc.y += __shfl_xor(acc.y, 16, 64);
        acc.z += __shfl_xor(acc.z, 16, 64); acc.w += __shfl_xor(acc.w, 16, 64);
        acc.x += __shfl_xor(acc.x, 32, 64); acc.y += __shfl_xor(acc.y, 32, 64);
        acc.z += __shfl_xor(acc.z, 32, 64); acc.w += __shfl_xor(acc.w, 32, 64);
        if (q == 0) {
            uint2 pk;
            pk.x = (unsigned)f2bfu(acc.x) | ((unsigned)f2bfu(acc.y) << 16);
            pk.y = (unsigned)f2bfu(acc.z) | ((unsigned)f2bfu(acc.w) << 16);
            *(uint2*)&aggt[wv][rr][sub * 2] = pk;
        }
    }
    // per-wave tile written by this wave only -> lgkmcnt orders, no barrier

    // ---- phase 4: two-hop MFMA transform + rownorm for this wave's 16 nodes ----
    int nb0 = p * 64 + wv * 16;
    if (nb0 >= NN) return;                   // tail partitions: whole waves only

    // A fragments: hop0 = x (f32->bf16 inline), hop1 = agg tile (already bf16)
    v8s ax[2], aa[2];
#pragma unroll
    for (int ks = 0; ks < 2; ++ks) {
        const float* px = x + (size_t)(nb0 + sub) * DD + ks * 32 + q * 8;
        float4 a0 = *(const float4*)px, a1 = *(const float4*)(px + 4);
        v8s w;
        w[0] = (short)f2bfu(a0.x); w[1] = (short)f2bfu(a0.y);
        w[2] = (short)f2bfu(a0.z); w[3] = (short)f2bfu(a0.w);
        w[4] = (short)f2bfu(a1.x); w[5] = (short)f2bfu(a1.y);
        w[6] = (short)f2bfu(a1.z); w[7] = (short)f2bfu(a1.w);
        ax[ks] = w;
        aa[ks] = *(const v8s*)&aggt[wv][sub][ks * 16 + q * 4];
    }

    // dt-sequential GEMM: transient W frags keep VGPR pressure low
    float h0v[4][4], h1v[4][4];
    float sr0[4] = {0,0,0,0}, sq0[4] = {0,0,0,0};
    float sr1[4] = {0,0,0,0}, sq1[4] = {0,0,0,0};
#pragma unroll
    for (int dt = 0; dt < 4; ++dt) {
        int nidx = dt * 16 + sub;
        float bi0 = b0[nidx], bi1 = b1[nidx];
        v8s w00 = *(const v8s*)(wb0 + nidx * 64 + q * 8);
        v8s w01 = *(const v8s*)(wb0 + nidx * 64 + 32 + q * 8);
        v8s w10 = *(const v8s*)(wb1 + nidx * 64 + q * 8);
        v8s w11 = *(const v8s*)(wb1 + nidx * 64 + 32 + q * 8);
        v4f c0 = (v4f){bi0, bi0, bi0, bi0};
        v4f c1 = (v4f){bi1, bi1, bi1, bi1};
        c0 = __builtin_amdgcn_mfma_f32_16x16x32_bf16(ax[0], w00, c0, 0, 0, 0);
        c0 = __builtin_amdgcn_mfma_f32_16x16x32_bf16(ax[1], w01, c0, 0, 0, 0);
        c1 = __builtin_amdgcn_mfma_f32_16x16x32_bf16(aa[0], w10, c1, 0, 0, 0);
        c1 = __builtin_amdgcn_mfma_f32_16x16x32_bf16(aa[1], w11, c1, 0, 0, 0);
#pragma unroll
        for (int r = 0; r < 4; ++r) {
            float h = fmaxf(c0[r], 0.f); h0v[dt][r] = h; sr0[r] += h; sq0[r] += h * h;
            float g = fmaxf(c1[r], 0.f); h1v[dt][r] = g; sr1[r] += g; sq1[r] += g * g;
        }
    }
#pragma unroll
    for (int off = 1; off < 16; off <<= 1) {
#pragma unroll
        for (int r = 0; r < 4; ++r) {
            sr0[r] += __shfl_xor(sr0[r], off, 64);
            sq0[r] += __shfl_xor(sq0[r], off, 64);
            sr1[r] += __shfl_xor(sr1[r], off, 64);
            sq1[r] += __shfl_xor(sq1[r], off, 64);
        }
    }

    float scl0[4], scl1[4], ofs0[4], ofs1[4];
#pragma unroll
    for (int dt = 0; dt < 4; ++dt) {
        int nidx = dt * 16 + sub;
        scl0[dt] = s0[nidx]; scl1[dt] = s1[nidx];
        ofs0[dt] = o0[nidx]; ofs1[dt] = o1[nidx];
    }

    const float inv = 1.0f / 64.0f;
#pragma unroll
    for (int r = 0; r < 4; ++r) {
        float m0 = sr0[r] * inv;
        float v0 = fmaxf(sq0[r] * inv - m0 * m0, 0.f) + 1e-9f;
        float m1 = sr1[r] * inv;
        float v1 = fmaxf(sq1[r] * inv - m1 * m1, 0.f) + 1e-9f;
        float rs0 = rsqrtf(v0), rs1 = rsqrtf(v1);
        int node = nb0 + q * 4 + r;           // always < NN (whole-wave tails)
#pragma unroll
        for (int dt = 0; dt < 4; ++dt) {
            float rv = (h0v[dt][r] - m0) * scl0[dt] * rs0 + ofs0[dt]
                     + (h1v[dt][r] - m1) * scl1[dt] * rs1 + ofs1[dt];
            out[(size_t)node * DD + dt * 16 + sub] = rv;  // 64B-coalesced per quad
        }
    }
}

extern "C" void kernel_launch(void* const* d_in, const int* in_sizes, int n_in,
                              void* d_out, int out_size, void* d_ws, size_t ws_size,
                              hipStream_t stream) {
    const float* x  = (const float*)d_in[0];
    const float* ev = (const float*)d_in[1];
    const float* W0 = (const float*)d_in[2];
    const float* b0 = (const float*)d_in[3];
    const float* s0 = (const float*)d_in[4];
    const float* o0 = (const float*)d_in[5];
    const float* W1 = (const float*)d_in[6];
    const float* b1 = (const float*)d_in[7];
    const float* s1 = (const float*)d_in[8];
    const float* o1 = (const float*)d_in[9];
    const int* row = (const int*)d_in[10];
    const int* col = (const int*)d_in[11];

    // ws byte layout (64B-aligned):
    //   gbcur: 0        (784 B, pad 1024)
    //   wb0:   1024     (8192 B)
    //   wb1:   9216     (8192 B)
    //   fcnt:  17408    (1568*4 = 6272 B, pad 6400)
    //   bslab: 23808    (196*10240*8 = 16,056,320 B)
    //   fslab: 16080128 (1563*1536*8 = 19,206,144 B)  -- total ~35.3 MB
    char* wsb = (char*)d_ws;
    int*  gbcur = (int*)wsb;
    unsigned short* wb0 = (unsigned short*)(wsb + 1024);
    unsigned short* wb1 = (unsigned short*)(wsb + 9216);
    int*  fcnt  = (int*)(wsb + 17408);
    int2* bslab = (int2*)(wsb + 23808);
    int2* fslab = (int2*)(wsb + 16080128);

    init_kernel<<<16, 256, 0, stream>>>(W0, W1, gbcur, wb0, wb1);
    bucket_scatter_kernel<<<NBK1, 256, 0, stream>>>(row, col, ev, gbcur, bslab);
    fine_scatter_kernel<<<NB, 256, 0, stream>>>(gbcur, bslab, fslab, fcnt);
    sort_pull_mfma_kernel<<<P, 256, 0, stream>>>(
        x, fcnt, fslab, wb0, wb1, b0, s0, o0, b1, s1, o1, (float*)d_out);
}